// Round 5
// baseline (254.854 us; speedup 1.0000x reference)
//
#include <hip/hip_runtime.h>
#include <cstdint>
#include <cstddef>

// Problem dims (fixed): B=1, S=4096, D_MODEL=1024, H=16, Dk=64.
#define S_LEN 4096
#define DMODEL 1024
#define NHEADS 16
#define DK 64
#define ACT (S_LEN * DMODEL)     // 4,194,304 elements
#define WELE (DMODEL * DMODEL)   // 1,048,576 elements

typedef __bf16 bf16;
typedef bf16  bf16x2 __attribute__((ext_vector_type(2)));
typedef bf16  bf16x4 __attribute__((ext_vector_type(4)));
typedef bf16  bf16x8 __attribute__((ext_vector_type(8)));
typedef float f32x4  __attribute__((ext_vector_type(4)));
typedef float f32x16 __attribute__((ext_vector_type(16)));
typedef unsigned int uint32x4v __attribute__((ext_vector_type(4)));

// ---- async global->LDS, 16B per lane, offset 0 only. LDS dest = wave-uniform
// base + lane*16. (Round-3-proven form.)
__device__ __forceinline__ void async16(const void* g, void* l) {
    __builtin_amdgcn_global_load_lds(
        (__attribute__((address_space(1))) void*)(uintptr_t)g,
        (__attribute__((address_space(3))) void*)(uintptr_t)l,
        16, 0, 0);
}

__device__ __forceinline__ float fast_exp2(float x) {
#if __has_builtin(__builtin_amdgcn_exp2f)
    return __builtin_amdgcn_exp2f(x);
#else
    return exp2f(x);
#endif
}

// pack two f32 -> one dword of 2 bf16 (compiler emits cvt + pack; m240: do
// NOT hand-write v_cvt_pk_bf16_f32)
__device__ __forceinline__ unsigned pk2(float a, float b) {
    bf16x2 t; t[0] = (bf16)a; t[1] = (bf16)b;
    return __builtin_bit_cast(unsigned, t);
}

// v_permlane32_swap_b32: swaps a's upper 32 lanes with b's lower 32 lanes.
__device__ __forceinline__ void pl32swap(unsigned &a, unsigned &b) {
    asm volatile("v_permlane32_swap_b32 %0, %1" : "+v"(a), "+v"(b));
}

__device__ __forceinline__ bf16x8 mkfrag(unsigned w0, unsigned w1, unsigned w2, unsigned w3) {
    uint32x4v u = { w0, w1, w2, w3 };
    return __builtin_bit_cast(bf16x8, u);
}

// ---------------------------------------------------------------------------
// fp32 -> bf16 converter, 7 tensors in one launch (y = 0..6).
// ---------------------------------------------------------------------------
__global__ void __launch_bounds__(256) cvt7(
    const float* a0, const float* a1, const float* a2,
    const float* w0, const float* w1, const float* w2, const float* w3,
    bf16* oa0, bf16* oa1, bf16* oa2,
    bf16* ow0, bf16* ow1, bf16* ow2, bf16* ow3,
    int nA, int nB)
{
    const float* s; bf16* d; int n4;
    switch (blockIdx.y) {
        case 0: s = a0; d = oa0; n4 = nA; break;
        case 1: s = a1; d = oa1; n4 = nA; break;
        case 2: s = a2; d = oa2; n4 = nA; break;
        case 3: s = w0; d = ow0; n4 = nB; break;
        case 4: s = w1; d = ow1; n4 = nB; break;
        case 5: s = w2; d = ow2; n4 = nB; break;
        default: s = w3; d = ow3; n4 = nB; break;
    }
    int i = blockIdx.x * 256 + threadIdx.x;
    if (i < n4) {
        float4 v = ((const float4*)s)[i];
        bf16x4 r = { (bf16)v.x, (bf16)v.y, (bf16)v.z, (bf16)v.w };
        ((bf16x4*)d)[i] = r;
    }
}

// ---------------------------------------------------------------------------
// MFMA sub-tile compute on a [128][32] LDS tile pair (r8-proven layout).
// ---------------------------------------------------------------------------
__device__ __forceinline__ void gemm_compute_128(
    const bf16* As, const bf16* Bs, f32x4 (&acc)[4][4],
    int wm, int wn, int l16, int quad)
{
    bf16x8 af[4], bfr[4];
#pragma unroll
    for (int i = 0; i < 4; ++i)
        af[i] = *(const bf16x8*)&As[(wm + i * 16 + l16) * 32 + quad * 8];
#pragma unroll
    for (int i = 0; i < 4; ++i)
        bfr[i] = *(const bf16x8*)&Bs[(wn + i * 16 + l16) * 32 + quad * 8];
#pragma unroll
    for (int mi = 0; mi < 4; ++mi)
#pragma unroll
        for (int ni = 0; ni < 4; ++ni)
            acc[mi][ni] = __builtin_amdgcn_mfma_f32_16x16x32_bf16(
                af[mi], bfr[ni], acc[mi][ni], 0, 0, 0);
}

// NT GEMM core, BK=64 as two proven BK=32 sub-tiles per barrier pair.
__device__ __forceinline__ void gemm_core_bk64(
    const bf16* __restrict__ A, const bf16* __restrict__ B,
    bf16* As, bf16* Bs, f32x4 (&acc)[4][4],
    int m0, int n0, int wm, int wn, int K)
{
    const int tid  = threadIdx.x;
    const int wave = tid >> 6;
    const int lane = tid & 63;
    const int quad = lane >> 4;
    const int l16  = lane & 15;

    const int srow = tid >> 2;
    const int scol = (tid & 3) * 8;
    const bf16* Ag = A + (size_t)(m0 + srow) * K + scol;
    const bf16* Bg = B + (size_t)(n0 + srow) * K + scol;
    char* lA = (char*)As + wave * 1024;
    char* lB = (char*)Bs + wave * 1024;

    for (int k0 = 0; k0 < K; k0 += 64) {
        async16(Ag,                       lA);
        async16(Ag + (size_t)64 * K,      lA + 4096);
        async16(Ag + 32,                  lA + 8192);
        async16(Ag + 32 + (size_t)64 * K, lA + 12288);
        async16(Bg,                       lB);
        async16(Bg + (size_t)64 * K,      lB + 4096);
        async16(Bg + 32,                  lB + 8192);
        async16(Bg + 32 + (size_t)64 * K, lB + 12288);
        Ag += 64; Bg += 64;
        __syncthreads();

        gemm_compute_128(As,        Bs,        acc, wm, wn, l16, quad);
        gemm_compute_128(As + 4096, Bs + 4096, acc, wm, wn, l16, quad);
        __syncthreads();
    }
}

// Fused QKV projection (r8 epilogues). blockIdx.z selects {Q,K,V}.
// Q/K: head-major bf16 [h][s][dk], 16B-chunk XOR-swizzled by (s&7) per row.
// V:   transposed TILED bf16 [h][T=t/64][dk][64], chunk-swizzled by (dk&7).
// Q pre-scaled by 0.125*log2e.
__global__ void __launch_bounds__(256) proj_qkv(
    const bf16* __restrict__ Xq, const bf16* __restrict__ Wq, const float* __restrict__ bq, bf16* __restrict__ Qo,
    const bf16* __restrict__ Xk, const bf16* __restrict__ Wk, const float* __restrict__ bk, bf16* __restrict__ Ko,
    const bf16* __restrict__ Xv, const bf16* __restrict__ Wv, const float* __restrict__ bv, bf16* __restrict__ Vo,
    float qscale)
{
    __shared__ __align__(16) bf16 As[2 * 128 * 32];   // 16 KB
    __shared__ __align__(16) bf16 Bs[2 * 128 * 32];   // 16 KB

    const int which = blockIdx.z;
    const bf16*  A    = (which == 0) ? Xq : (which == 1) ? Xk : Xv;
    const bf16*  Bw   = (which == 0) ? Wq : (which == 1) ? Wk : Wv;
    const float* bias = (which == 0) ? bq : (which == 1) ? bk : bv;
    const float  scale = (which == 0) ? qscale : 1.0f;

    const int tid  = threadIdx.x;
    const int wave = tid >> 6;
    const int lane = tid & 63;
    const int quad = lane >> 4;
    const int l16  = lane & 15;
    const int m0 = blockIdx.x * 128;
    const int n0 = blockIdx.y * 128;
    const int wm = (wave & 1) * 64;
    const int wn = (wave >> 1) * 64;

    f32x4 acc[4][4] = {};
    gemm_core_bk64(A, Bw, As, Bs, acc, m0, n0, wm, wn, DMODEL);

    // C/D layout: col(n) = lane&15, row(m) = quad*4 + reg
    if (which < 2) {
        bf16* out = (which == 0) ? Qo : Ko;
#pragma unroll
        for (int mi = 0; mi < 4; ++mi)
#pragma unroll
            for (int ni = 0; ni < 4; ++ni) {
                const int n = n0 + wn + ni * 16 + l16;
                const float bn = bias[n];
                const int dk = n & 63;
                const int cc = dk >> 3, ee = dk & 7;
                const size_t hb = (size_t)(n >> 6) * S_LEN * DK;
#pragma unroll
                for (int r = 0; r < 4; ++r) {
                    const int m = m0 + wm + mi * 16 + quad * 4 + r;
                    const int pdk = ((cc ^ (m & 7)) << 3) | ee;   // XOR swizzle by s-row
                    out[hb + (size_t)m * DK + pdk] = (bf16)((acc[mi][ni][r] + bn) * scale);
                }
            }
    } else {
        // V^T tiled: Vo[h][T][dk][64], 8-elem chunk (tt>>3) swizzled by ^(dk&7)
#pragma unroll
        for (int mi = 0; mi < 4; ++mi)
#pragma unroll
            for (int ni = 0; ni < 4; ++ni) {
                const int n = n0 + wn + ni * 16 + l16;     // h*64 + dk
                const float bn = bias[n];
                const int dk = n & 63;
                const size_t hb = (size_t)(n >> 6) * (64 * S_LEN);
                const int mbase = m0 + wm + mi * 16 + quad * 4;   // t, 4 contiguous
                const int T  = mbase >> 6;
                const int tt = mbase & 63;
                const int pos = (((tt >> 3) ^ (dk & 7)) << 3) | (tt & 7);
                bf16x4 r4;
#pragma unroll
                for (int r = 0; r < 4; ++r) r4[r] = (bf16)(acc[mi][ni][r] + bn);
                *(bf16x4*)&Vo[hb + (size_t)T * 4096 + dk * 64 + pos] = r4;
            }
    }
}

// Output GEMM, 64x128 tile (512 blocks = 2/CU), r9-proven.
__global__ void __launch_bounds__(256) gemm_out(
    const bf16* __restrict__ A, const bf16* __restrict__ Bw,
    const float* __restrict__ bias, float* __restrict__ out)
{
    __shared__ __align__(16) bf16 As[64 * 32];    // 4 KB
    __shared__ __align__(16) bf16 Bs[128 * 32];   // 8 KB

    const int tid  = threadIdx.x;
    const int wave = tid >> 6;
    const int lane = tid & 63;
    const int quad = lane >> 4;
    const int l16  = lane & 15;
    const int m0 = blockIdx.x * 64;
    const int n0 = blockIdx.y * 128;
    const int wm = (wave & 1) * 32;
    const int wn = (wave >> 1) * 64;

    const int srow = tid >> 2;
    const int scol = (tid & 3) * 8;
    const bf16* Ag  = A  + (size_t)(m0 + srow) * DMODEL + scol;
    const bf16* Bg  = Bw + (size_t)(n0 + srow) * DMODEL + scol;
    const bf16* Bg2 = Bg + (size_t)64 * DMODEL;

    f32x4 acc[2][4] = {};
    for (int k0 = 0; k0 < DMODEL; k0 += 32) {
        async16(Ag,  (char*)As + wave * 1024);
        async16(Bg,  (char*)Bs + wave * 1024);
        async16(Bg2, (char*)Bs + 4096 + wave * 1024);
        Ag += 32; Bg += 32; Bg2 += 32;
        __syncthreads();

        bf16x8 af[2], bfr[4];
#pragma unroll
        for (int i = 0; i < 2; ++i)
            af[i] = *(const bf16x8*)&As[(wm + i * 16 + l16) * 32 + quad * 8];
#pragma unroll
        for (int i = 0; i < 4; ++i)
            bfr[i] = *(const bf16x8*)&Bs[(wn + i * 16 + l16) * 32 + quad * 8];

#pragma unroll
        for (int mi = 0; mi < 2; ++mi)
#pragma unroll
            for (int ni = 0; ni < 4; ++ni)
                acc[mi][ni] = __builtin_amdgcn_mfma_f32_16x16x32_bf16(
                    af[mi], bfr[ni], acc[mi][ni], 0, 0, 0);
        __syncthreads();
    }

#pragma unroll
    for (int mi = 0; mi < 2; ++mi)
#pragma unroll
        for (int ni = 0; ni < 4; ++ni) {
            const int n = n0 + wn + ni * 16 + l16;
            const float bn = bias[n];
#pragma unroll
            for (int r = 0; r < 4; ++r) {
                const int m = m0 + wm + mi * 16 + quad * 4 + r;
                out[(size_t)m * DMODEL + n] = acc[mi][ni][r] + bn;
            }
        }
}

// ---------------------------------------------------------------------------
// Flash attention — ROUND-5: 3-buffer K/V ring + counted vmcnt barrier (T4).
//
//  Why: r4 counters show no saturated pipe (Mfma 33, VALU 42, DS ~50%,
//  staging ~50% of delivery) at 2 waves/SIMD — latency-bound. The compiler's
//  __syncthreads emits s_waitcnt vmcnt(0) which drains the JUST-issued
//  prefetch every iteration, exposing L3/HBM latency and coupling all 8
//  waves to the slowest load. Fix per T3/T4: prefetch 2 tiles ahead into a
//  3-buffer ring; end-of-iter sync = asm s_waitcnt vmcnt(2) (the 2 loads
//  just issued may stay in flight) + raw s_barrier + sched_barrier(0)
//  (rule 18). Tile it+1's loads were issued a full window (~3400 cyc) ago
//  -> barrier wait ~0.
//
//  Hazard audit: iter-i prefetch writes buf[(i+2)%3], last READ at iter i-1;
//  those ds_reads were consumed by MFMAs before barrier i-1 -> safe. vmcnt
//  is per-wave FIFO (2 loads/iter), so vmcnt(2) at barrier i proves every
//  wave's tile-(i+1) loads landed before anyone reads them at iter i+1.
//
//  Per-wave structure unchanged from r4 (8 waves x 32 q-rows, 32x32x16 MFMA,
//  in-register P via pk2+permlane32). Grid (S/256, H) = 256 blocks = 1/CU.
//  LDS = Qs 32K + Ks 24K + Vs 24K = 80 KB.
// ---------------------------------------------------------------------------
__global__ void __launch_bounds__(512) flash_attn(
    const bf16* __restrict__ Q, const bf16* __restrict__ Kh,
    const bf16* __restrict__ Vt, bf16* __restrict__ ctx)
{
    __shared__ __align__(16) bf16 Qs[256 * 64];      // 32 KB
    __shared__ __align__(16) bf16 Ks[3][64 * 64];    // 24 KB (3-ring)
    __shared__ __align__(16) bf16 Vs[3][64 * 64];    // 24 KB (3-ring)

    const int tid  = threadIdx.x;
    const int wave = tid >> 6;           // 0..7
    const int lane = tid & 63;
    const int l31  = lane & 31;
    const int hi   = lane >> 5;          // 0 = lanes 0..31, 1 = lanes 32..63
    const int x7   = lane & 7;           // row&7 swizzle key (row = *&31)
    const int s0 = blockIdx.x * 256;
    const int h  = blockIdx.y;

    const bf16* Kg = Kh + (size_t)h * S_LEN * DK + tid * 8;
    const bf16* Vg = Vt + (size_t)h * (64 * S_LEN) + tid * 8;   // tiled V

    // prologue: stage Q tile (32 KB) + K/V tiles 0 and 1
    {
        const bf16* Qg = Q + (size_t)h * S_LEN * DK + (size_t)s0 * DK + tid * 8;
#pragma unroll
        for (int j = 0; j < 4; ++j)
            async16(Qg + j * 4096, (char*)Qs + j * 8192 + wave * 1024);
    }
    async16(Kg, (char*)Ks + wave * 1024);
    async16(Vg, (char*)Vs + wave * 1024);
    Kg += 4096; Vg += 4096;
    async16(Kg, (char*)Ks + 8192 + wave * 1024);
    async16(Vg, (char*)Vs + 8192 + wave * 1024);
    Kg += 4096; Vg += 4096;
    // wait Q + tile0 (tile1's 2 loads may remain in flight), then barrier
    asm volatile("s_waitcnt vmcnt(2)" ::: "memory");
    __builtin_amdgcn_s_barrier();
    __builtin_amdgcn_sched_barrier(0);

    // Q B-fragments: qf[ks] = Q[s = wave*32 + l31][k = ks*16 + hi*8 + 0..7]
    bf16x8 qf[4];
    {
        const bf16* qb = &Qs[(wave * 32 + l31) * 64];
#pragma unroll
        for (int ks = 0; ks < 4; ++ks)
            qf[ks] = *(const bf16x8*)(qb + ((((ks << 1) + hi) ^ x7) << 3));
    }

    f32x16 od[2] = {};
    float lsum = 0.0f;

    // per-tile compute from ring buffer cb (reads Ks[cb]/Vs[cb], accumulates od/lsum)
    auto compute = [&](int cb) {
        const bf16* Kc = &Ks[cb][0];
        const bf16* Vc = &Vs[cb][0];

        f32x16 st[2] = {};
        __builtin_amdgcn_s_setprio(1);
#pragma unroll
        for (int tt = 0; tt < 2; ++tt) {
            const bf16* kb = &Kc[(tt * 32 + l31) * 64];
#pragma unroll
            for (int ks = 0; ks < 4; ++ks) {
                bf16x8 kf = *(const bf16x8*)(kb + ((((ks << 1) + hi) ^ x7) << 3));
                st[tt] = __builtin_amdgcn_mfma_f32_32x32x16_bf16(kf, qf[ks], st[tt], 0, 0, 0);
            }
        }
        __builtin_amdgcn_s_setprio(0);

        // softmax-lite + in-register P->B-frag build.
        bf16x8 pf[4];
#pragma unroll
        for (int tt = 0; tt < 2; ++tt) {
            float p[16];
#pragma unroll
            for (int r = 0; r < 16; ++r) {
                p[r] = fast_exp2(st[tt][r]);
                lsum += p[r];
            }
#pragma unroll
            for (int w = 0; w < 2; ++w) {
                const int G = w * 8;
                unsigned A0 = pk2(p[G + 0], p[G + 1]);
                unsigned A1 = pk2(p[G + 2], p[G + 3]);
                unsigned B0 = pk2(p[G + 4], p[G + 5]);
                unsigned B1 = pk2(p[G + 6], p[G + 7]);
                pl32swap(A0, B0);
                pl32swap(A1, B1);
                pf[tt * 2 + w] = mkfrag(A0, A1, B0, B1);
            }
        }

        // O^T += V^T_frag * P_frag
        __builtin_amdgcn_s_setprio(1);
#pragma unroll
        for (int dd = 0; dd < 2; ++dd) {
            const bf16* vb = &Vc[(dd * 32 + l31) * 64];
#pragma unroll
            for (int ks = 0; ks < 4; ++ks) {
                bf16x8 vf = *(const bf16x8*)(vb + ((((ks << 1) + hi) ^ x7) << 3));
                od[dd] = __builtin_amdgcn_mfma_f32_32x32x16_bf16(vf, pf[ks], od[dd], 0, 0, 0);
            }
        }
        __builtin_amdgcn_s_setprio(0);
    };

    int cur = 0;
    for (int it = 0; it < 62; ++it) {
        // prefetch tile it+2 into ring slot (cur+2)%3
        int nb = cur + 2; if (nb >= 3) nb -= 3;
        async16(Kg, (char*)Ks + nb * 8192 + wave * 1024);
        async16(Vg, (char*)Vs + nb * 8192 + wave * 1024);
        Kg += 4096; Vg += 4096;

        compute(cur);

        // counted sync: only this iter's 2 loads may remain in flight.
        asm volatile("s_waitcnt vmcnt(2)" ::: "memory");
        __builtin_amdgcn_s_barrier();
        __builtin_amdgcn_sched_barrier(0);
        cur = (cur + 1 == 3) ? 0 : cur + 1;
    }
    // tile 62: no prefetch left; tile 63's loads (issued at it=61) must land.
    compute(cur);
    asm volatile("s_waitcnt vmcnt(0)" ::: "memory");
    __builtin_amdgcn_s_barrier();
    __builtin_amdgcn_sched_barrier(0);
    cur = (cur + 1 == 3) ? 0 : cur + 1;
    // tile 63: last compute, no sync needed after (epilogue is per-wave).
    compute(cur);

    // epilogue: lane owns s-col = s0 + wave*32 + l31; partner (lane^32) has
    // the other 32 t-values of the softmax denominator.
    lsum += __shfl_xor(lsum, 32);
    const float rinv = 1.0f / lsum;
    const int s = s0 + wave * 32 + l31;
#pragma unroll
    for (int dd = 0; dd < 2; ++dd)
#pragma unroll
        for (int g = 0; g < 4; ++g) {
            bf16x4 r4;
#pragma unroll
            for (int r = 0; r < 4; ++r)
                r4[r] = (bf16)(od[dd][g * 4 + r] * rinv);
            *(bf16x4*)&ctx[(size_t)s * DMODEL + h * DK + dd * 32 + g * 8 + hi * 4] = r4;
        }
}

// ---------------------------------------------------------------------------
extern "C" void kernel_launch(void* const* d_in, const int* in_sizes, int n_in,
                              void* d_out, int out_size, void* d_ws, size_t ws_size,
                              hipStream_t stream)
{
    (void)in_sizes; (void)n_in; (void)out_size; (void)ws_size;
    const float* q  = (const float*)d_in[0];
    const float* k  = (const float*)d_in[1];
    const float* v  = (const float*)d_in[2];
    const float* Wq = (const float*)d_in[3];
    const float* bq = (const float*)d_in[4];
    const float* Wk = (const float*)d_in[5];
    const float* bk = (const float*)d_in[6];
    const float* Wv = (const float*)d_in[7];
    const float* bv = (const float*)d_in[8];
    const float* Wo = (const float*)d_in[9];
    const float* bo = (const float*)d_in[10];

    // workspace layout (bf16), total exactly 64 MB
    bf16* Xq  = (bf16*)d_ws;
    bf16* Xk  = Xq  + ACT;
    bf16* Xv  = Xk  + ACT;
    bf16* Wqb = Xv  + ACT;
    bf16* Wkb = Wqb + WELE;
    bf16* Wvb = Wkb + WELE;
    bf16* Wob = Wvb + WELE;
    bf16* Qh  = Wob + WELE;  // [h][s][dk] swizzled
    bf16* Kh  = Qh  + ACT;   // [h][t][dk] swizzled
    bf16* Vt  = Kh  + ACT;   // [h][T][dk][64] swizzled, tiled
    bf16* CTX = Vt  + ACT;   // [s][1024]

    cvt7<<<dim3(ACT / 4 / 256, 7), 256, 0, stream>>>(
        q, k, v, Wq, Wk, Wv, Wo,
        Xq, Xk, Xv, Wqb, Wkb, Wvb, Wob, ACT / 4, WELE / 4);

    const float qscale = 0.125f * 1.4426950408889634f;  // 1/sqrt(Dk) * log2(e)
    proj_qkv<<<dim3(S_LEN / 128, DMODEL / 128, 3), 256, 0, stream>>>(
        Xq, Wqb, bq, Qh, Xk, Wkb, bk, Kh, Xv, Wvb, bv, Vt, qscale);

    flash_attn<<<dim3(S_LEN / 256, NHEADS), 512, 0, stream>>>(Qh, Kh, Vt, CTX);

    gemm_out<<<dim3(S_LEN / 64, DMODEL / 128), 256, 0, stream>>>(CTX, Wob, bo, (float*)d_out);
}